// Round 24
// baseline (117.744 us; speedup 1.0000x reference)
//
#include <hip/hip_runtime.h>

// DynamicMemoryCell: B=8, N=2048, IN=256, MEM=256, CTX=128
// out0 = new_memory [8,2048,256] f32 ; out1 = attention_probs [8,2048,2048] f32
// Wv/value/context dead in reference -> skipped.
//
// R23 = R22 (best, 99.3us) with k0 DELETED: every consumer converts its fp32
// weights in registers (R17-proven identical rounding: h=(half)w, lo=(half)(w-h)).
// Chain (big ws): k1 -> k3a -> kDE=[k3b || k2ru] -> k2c.
// ws holds only Q, K, t, u (+part at front). Fallback serial path same bodies.

typedef _Float16 half8 __attribute__((ext_vector_type(8)));
typedef float floatx4 __attribute__((ext_vector_type(4)));

#define MFMA16(a, b, c) __builtin_amdgcn_mfma_f32_16x16x32_f16((a), (b), (c), 0, 0, 0)

// ws layout (units: _Float16). part (f32, 256 KB) aliases ws front (nothing else there).
#define OFF_Q   524288
#define OFF_K   2621440
#define OFF_T   4718592
#define OFF_U   8912896
// big-ws end = 13107200 halves = 26,214,400 bytes.

__device__ __forceinline__ void gload16(const void* g, void* l) {
  __builtin_amdgcn_global_load_lds((const __attribute__((address_space(1))) unsigned int*)g,
                                   (__attribute__((address_space(3))) unsigned int*)l, 16, 0, 0);
}

// ---------------------------------------------------------------- K1: Q/K projection (W hi/lo converted in registers)
__global__ __launch_bounds__(512) void k1_proj(
    const float* __restrict__ input, const float* __restrict__ prev,
    const float* __restrict__ Wq, const float* __restrict__ bq,
    const float* __restrict__ Wk, const float* __restrict__ bk,
    _Float16* __restrict__ ws)
{
  __shared__ char smem[2 * 8192];   // 16 rows x 512B (x fp16)
  const int which = blockIdx.y;
  const float* x = which ? prev : input;
  const float* Wf = which ? Wk : Wq;    // fp32 [128][256]
  const float* bias = which ? bk : bq;
  _Float16* out = ws + (which ? OFF_K : OFF_Q);

  const int tid = threadIdx.x, w = tid >> 6, l = tid & 63;
  const int lr = l & 15, lg = l >> 4;
  const int rows0 = blockIdx.x * 64;
  const int c = w * 16 + lr;

  half8 bh[8], blo[8];
#pragma unroll
  for (int ks = 0; ks < 8; ++ks) {
    floatx4 w0 = *(const floatx4*)(Wf + (size_t)c * 256 + ks * 32 + lg * 8);
    floatx4 w1 = *(const floatx4*)(Wf + (size_t)c * 256 + ks * 32 + lg * 8 + 4);
    half8 h, lo;
#pragma unroll
    for (int j = 0; j < 4; ++j) {
      _Float16 h0 = (_Float16)w0[j];
      h[j] = h0; lo[j] = (_Float16)(w0[j] - (float)h0);
      _Float16 h1 = (_Float16)w1[j];
      h[4 + j] = h1; lo[4 + j] = (_Float16)(w1[j] - (float)h1);
    }
    bh[ks] = h; blo[ks] = lo;
  }
  const float bv = bias[c];

  const int srow = tid >> 5, scol = (tid & 31) * 8;
  const int ssz = (srow & 7) << 4;
  floatx4 st0, st1;

#define K1_LOAD(ch) { const float* src = x + ((size_t)rows0 + (ch) * 16 + srow) * 256 + scol; \
  st0 = *(const floatx4*)src; st1 = *(const floatx4*)(src + 4); }
#define K1_WRITE(ch) { char* bufw = smem + ((ch) & 1) * 8192; \
  half8 h; \
  _Pragma("unroll") for (int j = 0; j < 4; ++j) { \
    h[j] = (_Float16)st0[j]; h[4+j] = (_Float16)st1[j]; } \
  *(half8*)(bufw + srow * 512 + ((scol * 2) ^ ssz)) = h; }

  K1_LOAD(0); K1_WRITE(0);
  __syncthreads();
#pragma unroll 1
  for (int ch = 0; ch < 4; ++ch) {
    if (ch < 3) K1_LOAD(ch + 1);
    const char* buf = smem + (ch & 1) * 8192;
    floatx4 acc = {0.f, 0.f, 0.f, 0.f};
    const int base = lr * 512, sz = (lr & 7) << 4;
#pragma unroll
    for (int ks = 0; ks < 8; ++ks) {
      half8 ah = *(const half8*)(buf + base + ((ks * 64 + lg * 16) ^ sz));
      acc = MFMA16(ah, bh[ks], acc);
      acc = MFMA16(ah, blo[ks], acc);
    }
#pragma unroll
    for (int j = 0; j < 4; ++j)
      out[((size_t)rows0 + ch * 16 + lg * 4 + j) * 128 + c] = (_Float16)(acc[j] + bv);
    if (ch < 3) K1_WRITE(ch + 1);
    __syncthreads();
  }
}

// ================================================================ role bodies
// k2ru body: reset + update gates; Wr/Wu fp32 converted in registers. job 0..511.
__device__ __forceinline__ void k2ru_body(
    char* smem, int job, int tid,
    const float* __restrict__ input, const float* __restrict__ prev,
    const float* __restrict__ Wr, const float* __restrict__ br,
    const float* __restrict__ Wu, const float* __restrict__ bu,
    _Float16* __restrict__ t_sc, _Float16* __restrict__ u_sc)
{
  const int w = tid >> 6, l = tid & 63;
  const int lr = l & 15, lg = l >> 4;
  const int rows0 = (job & 127) * 128;
  const int isU = w >> 2;
  const int c = (job >> 7) * 64 + (w & 3) * 16 + lr;

  const float* Wf = isU ? Wu : Wr;      // fp32 [256][512]
  half8 bw[16];
#pragma unroll
  for (int ks = 0; ks < 16; ++ks) {
    floatx4 w0 = *(const floatx4*)(Wf + (size_t)c * 512 + ks * 32 + lg * 8);
    floatx4 w1 = *(const floatx4*)(Wf + (size_t)c * 512 + ks * 32 + lg * 8 + 4);
    half8 h;
#pragma unroll
    for (int j = 0; j < 4; ++j) { h[j] = (_Float16)w0[j]; h[4 + j] = (_Float16)w1[j]; }
    bw[ks] = h;
  }
  const float bv = (isU ? bu : br)[c];

  const int srow = tid >> 5, scol = (tid & 31) * 8;
  const int ssz = (srow & 7) << 4;
  floatx4 sI0, sI1, sP0, sP1;

#define K2RU_LOAD(ch) { \
  const float* si = input + ((size_t)rows0 + (ch) * 16 + srow) * 256 + scol; \
  const float* sp = prev  + ((size_t)rows0 + (ch) * 16 + srow) * 256 + scol; \
  sI0 = *(const floatx4*)si; sI1 = *(const floatx4*)(si + 4); \
  sP0 = *(const floatx4*)sp; sP1 = *(const floatx4*)(sp + 4); }
#define K2RU_WRITE(ch) { char* bufw = smem + ((ch) & 1) * 16384; \
  half8 hi, hp; \
  _Pragma("unroll") for (int j = 0; j < 4; ++j) { \
    hi[j] = (_Float16)sI0[j]; hi[4+j] = (_Float16)sI1[j]; \
    hp[j] = (_Float16)sP0[j]; hp[4+j] = (_Float16)sP1[j]; } \
  int o = srow * 1024 + ((scol * 2) ^ ssz); \
  *(half8*)(bufw + o) = hi; *(half8*)(bufw + o + 512) = hp; }

  K2RU_LOAD(0); K2RU_WRITE(0);
  __syncthreads();
#pragma unroll 1
  for (int ch = 0; ch < 8; ++ch) {
    if (ch < 7) K2RU_LOAD(ch + 1);
    const char* buf = smem + (ch & 1) * 16384;
    floatx4 acc = {0.f, 0.f, 0.f, 0.f};
    const int base = lr * 1024, sz = (lr & 7) << 4;
#pragma unroll
    for (int ks = 0; ks < 16; ++ks) {   // ks>=8 lands in [512,1024) = prev half
      half8 a = *(const half8*)(buf + base + ((ks * 64 + lg * 16) ^ sz));
      acc = MFMA16(a, bw[ks], acc);
    }
#pragma unroll
    for (int j = 0; j < 4; ++j) {
      const int crow = lg * 4 + j;
      const size_t grow = (size_t)rows0 + ch * 16 + crow;
      float g = 1.f / (1.f + __expf(-(acc[j] + bv)));
      if (!isU) {
        float m = (float)*(const _Float16*)(buf + crow * 1024 + 512 + ((c * 2) ^ ((crow & 7) << 4)));
        t_sc[grow * 256 + c] = (_Float16)(g * m);
      } else {
        u_sc[grow * 256 + c] = (_Float16)g;
      }
    }
    if (ch < 7) K2RU_WRITE(ch + 1);
    __syncthreads();
  }
}

// ---------------------------------------------------------------- shared macros for k2c / k3 roles
#define K2C_LOAD(ch) { \
  const float* si = input + ((size_t)rows0 + (ch) * 16 + srow) * 256 + scol; \
  sI0 = *(const floatx4*)si; sI1 = *(const floatx4*)(si + 4); \
  sT = *(const half8*)(t_sc + ((size_t)rows0 + (ch) * 16 + srow) * 256 + scol); }
#define K2C_WRITE(ch) { char* bufw = smemc + ((ch) & 1) * 16384; \
  half8 hi; \
  _Pragma("unroll") for (int j = 0; j < 4; ++j) { hi[j] = (_Float16)sI0[j]; hi[4+j] = (_Float16)sI1[j]; } \
  int o = srow * 1024 + ((scol * 2) ^ ssz); \
  *(half8*)(bufw + o) = hi; *(half8*)(bufw + o + 512) = sT; }

#define K3_STAGE(Kg, dst, ch) { \
  const char* g_ = (Kg) + (ch) * 32768; \
  _Pragma("unroll") for (int i_ = 0; i_ < 4; ++i_) { \
    int o_ = w * 1024 + i_ * 8192 + l * 16; \
    int row_ = o_ >> 8, col_ = o_ & 255; \
    gload16(g_ + row_ * 256 + (col_ ^ ((row_ & 7) << 4)), (dst) + w * 1024 + i_ * 8192); } }

// k2c body (candidate + combine -> out0); Wc fp32 converted in registers.
__device__ __forceinline__ void k2c_body(
    char* smemc, int job, int tid,
    const float* __restrict__ input, const float* __restrict__ prev,
    const float* __restrict__ Wc, const float* __restrict__ bc,
    const _Float16* __restrict__ t_sc, const _Float16* __restrict__ u_sc,
    float* __restrict__ out0)
{
  const int w = tid >> 6, l = tid & 63;
  const int lr = l & 15, lg = l >> 4;
  const int rows0 = (job & 255) * 64;
  const int c = (job >> 8) * 128 + w * 16 + lr;

  half8 bw[16];
#pragma unroll
  for (int ks = 0; ks < 16; ++ks) {
    floatx4 w0 = *(const floatx4*)(Wc + (size_t)c * 512 + ks * 32 + lg * 8);
    floatx4 w1 = *(const floatx4*)(Wc + (size_t)c * 512 + ks * 32 + lg * 8 + 4);
    half8 h;
#pragma unroll
    for (int j = 0; j < 4; ++j) { h[j] = (_Float16)w0[j]; h[4 + j] = (_Float16)w1[j]; }
    bw[ks] = h;
  }
  const float bv = bc[c];

  const int srow = tid >> 5, scol = (tid & 31) * 8;
  const int ssz = (srow & 7) << 4;
  floatx4 sI0, sI1;
  half8 sT;

  K2C_LOAD(0); K2C_WRITE(0);
  __syncthreads();
#pragma unroll 1
  for (int ch = 0; ch < 4; ++ch) {
    if (ch < 3) K2C_LOAD(ch + 1);
    const char* buf = smemc + (ch & 1) * 16384;
    floatx4 acc = {0.f, 0.f, 0.f, 0.f};
    const int base = lr * 1024, sz = (lr & 7) << 4;
#pragma unroll
    for (int ks = 0; ks < 16; ++ks) {   // ks>=8 = t half
      half8 a = *(const half8*)(buf + base + ((ks * 64 + lg * 16) ^ sz));
      acc = MFMA16(a, bw[ks], acc);
    }
#pragma unroll
    for (int j = 0; j < 4; ++j) {
      const size_t grow = (size_t)rows0 + ch * 16 + lg * 4 + j;
      float e2 = __expf(2.f * (acc[j] + bv));
      float cg = (e2 - 1.f) / (e2 + 1.f);
      float u = (float)u_sc[grow * 256 + c];
      float m = prev[grow * 256 + c];
      out0[grow * 256 + c] = (1.f - u) * m + u * cg;
    }
    if (ch < 3) K2C_WRITE(ch + 1);
    __syncthreads();
  }
}

// k3b body (recompute + normalize + store out1)
__device__ __forceinline__ void k3b_body(
    char* smem, int job, int tid,
    const _Float16* __restrict__ ws, const float* __restrict__ part,
    float* __restrict__ out1)
{
  const int w = tid >> 6, l = tid & 63;
  const int lr = l & 15, lg = l >> 4;
  const int b = job & 7, q0 = ((job >> 3) & 15) * 128, kh = job >> 7;

  const int q = q0 + w * 16 + lr;
  const _Float16* Q = ws + OFF_Q + ((size_t)b * 2048 + q0 + w * 16) * 128;
  const char* Kg = (const char*)(ws + OFF_K + ((size_t)b * 2048 + kh * 512) * 128);

  half8 qf[4];
#pragma unroll
  for (int ks = 0; ks < 4; ++ks)
    qf[ks] = *(const half8*)(Q + (size_t)lr * 128 + ks * 32 + lg * 8);
  const float inv = 1.f / (part[(size_t)(b * 4 + 0) * 2048 + q] +
                           part[(size_t)(b * 4 + 1) * 2048 + q] +
                           part[(size_t)(b * 4 + 2) * 2048 + q] +
                           part[(size_t)(b * 4 + 3) * 2048 + q]);

  char* kbuf0 = smem; char* kbuf1 = smem + 32768;
  K3_STAGE(Kg, kbuf0, 0);
  __syncthreads();

  float* orow = out1 + ((size_t)b * 2048 + q) * 2048 + kh * 512;
#pragma unroll 1
  for (int ch = 0; ch < 4; ++ch) {
    if (ch < 3) K3_STAGE(Kg, ((ch + 1) & 1) ? kbuf1 : kbuf0, ch + 1);
    const char* buf = (ch & 1) ? kbuf1 : kbuf0;
#pragma unroll
    for (int kt = 0; kt < 8; ++kt) {
      const int kk = kt * 16 + lr;
      const int kbase = kk * 256, ksz = (kk & 7) << 4;
      half8 kf[4];
#pragma unroll
      for (int ks = 0; ks < 4; ++ks)
        kf[ks] = *(const half8*)(buf + kbase + ((ks * 64 + lg * 16) ^ ksz));
      floatx4 acc = {0.f, 0.f, 0.f, 0.f};
#pragma unroll
      for (int ks = 0; ks < 4; ++ks) acc = MFMA16(kf[ks], qf[ks], acc);
      floatx4 v;
#pragma unroll
      for (int j = 0; j < 4; ++j) v[j] = __expf(acc[j] - 14.f) * inv;
      *(floatx4*)(orow + ch * 128 + kt * 16 + lg * 4) = v;
    }
    __syncthreads();
  }
}

// ---------------------------------------------------------------- K3a: softmax row-sums (pass 1)
// grid (8, 16, 4) x 512. Block = 128 q-rows x 512 keys. 8 waves split q (16 rows each).
__global__ __launch_bounds__(512) void k3a_sums(
    const _Float16* __restrict__ ws, float* __restrict__ part)
{
  __shared__ char kbuf[2][32768];
  const int b = blockIdx.x, q0 = blockIdx.y * 128, kh = blockIdx.z;
  const int tid = threadIdx.x, w = tid >> 6, l = tid & 63;
  const int lr = l & 15, lg = l >> 4;

  const _Float16* Q = ws + OFF_Q + ((size_t)b * 2048 + q0 + w * 16) * 128;
  const char* Kg = (const char*)(ws + OFF_K + ((size_t)b * 2048 + kh * 512) * 128);

  half8 qf[4];
#pragma unroll
  for (int ks = 0; ks < 4; ++ks)
    qf[ks] = *(const half8*)(Q + (size_t)lr * 128 + ks * 32 + lg * 8);

  K3_STAGE(Kg, kbuf[0], 0);
  __syncthreads();

  float se = 0.f;
#pragma unroll 1
  for (int ch = 0; ch < 4; ++ch) {
    if (ch < 3) K3_STAGE(Kg, kbuf[(ch + 1) & 1], ch + 1);
    const char* buf = kbuf[ch & 1];
#pragma unroll
    for (int kt = 0; kt < 8; ++kt) {
      const int kk = kt * 16 + lr;
      const int kbase = kk * 256, ksz = (kk & 7) << 4;
      half8 kf[4];
#pragma unroll
      for (int ks = 0; ks < 4; ++ks)
        kf[ks] = *(const half8*)(buf + kbase + ((ks * 64 + lg * 16) ^ ksz));
      floatx4 acc = {0.f, 0.f, 0.f, 0.f};
#pragma unroll
      for (int ks = 0; ks < 4; ++ks) acc = MFMA16(kf[ks], qf[ks], acc);
#pragma unroll
      for (int j = 0; j < 4; ++j) se += __expf(acc[j] - 14.f);
    }
    __syncthreads();
  }
  se += __shfl_xor(se, 16);
  se += __shfl_xor(se, 32);
  if (lg == 0)
    part[((size_t)b * 4 + kh) * 2048 + q0 + w * 16 + lr] = se;
}

// ---------------------------------------------------------------- fat kDE = [k3b (first 512) || k2ru (next 512)]
__global__ __launch_bounds__(512, 4) void kDE(
    const float* __restrict__ input, const float* __restrict__ prev,
    const float* __restrict__ Wr, const float* __restrict__ br,
    const float* __restrict__ Wu, const float* __restrict__ bu,
    const _Float16* __restrict__ ws, const float* __restrict__ part,
    _Float16* __restrict__ t_sc, _Float16* __restrict__ u_sc,
    float* __restrict__ out1)
{
  __shared__ char smem[65536];
  if (blockIdx.x < 512)
    k3b_body(smem, blockIdx.x, threadIdx.x, ws, part, out1);
  else
    k2ru_body(smem, blockIdx.x - 512, threadIdx.x, input, prev, Wr, br, Wu, bu, t_sc, u_sc);
}

// ---------------------------------------------------------------- standalone kernels
__global__ __launch_bounds__(512) void k2ru_kernel(
    const float* __restrict__ input, const float* __restrict__ prev,
    const float* __restrict__ Wr, const float* __restrict__ br,
    const float* __restrict__ Wu, const float* __restrict__ bu,
    _Float16* __restrict__ t_sc, _Float16* __restrict__ u_sc)
{
  __shared__ char smem[2 * 16384];
  k2ru_body(smem, (blockIdx.y << 7) | blockIdx.x, threadIdx.x,
            input, prev, Wr, br, Wu, bu, t_sc, u_sc);
}

__global__ __launch_bounds__(512) void k2c_kernel(
    const float* __restrict__ input, const float* __restrict__ prev,
    const float* __restrict__ Wc, const float* __restrict__ bc,
    const _Float16* __restrict__ t_sc, const _Float16* __restrict__ u_sc,
    float* __restrict__ out0)
{
  __shared__ char smemc[2 * 16384];
  k2c_body(smemc, blockIdx.x, threadIdx.x, input, prev, Wc, bc, t_sc, u_sc, out0);
}

__global__ __launch_bounds__(512) void k3b_kernel(
    const _Float16* __restrict__ ws, const float* __restrict__ part,
    float* __restrict__ out1)
{
  __shared__ char smem[65536];
  k3b_body(smem, blockIdx.x, threadIdx.x, ws, part, out1);
}

// ----------------------------------------------------------------
extern "C" void kernel_launch(void* const* d_in, const int* in_sizes, int n_in,
                              void* d_out, int out_size, void* d_ws, size_t ws_size,
                              hipStream_t stream)
{
  const float* input = (const float*)d_in[0];
  const float* prev  = (const float*)d_in[1];
  const float* Wq = (const float*)d_in[2];
  const float* bq = (const float*)d_in[3];
  const float* Wk = (const float*)d_in[4];
  const float* bk = (const float*)d_in[5];
  const float* Wu = (const float*)d_in[8];
  const float* bu = (const float*)d_in[9];
  const float* Wr = (const float*)d_in[10];
  const float* br = (const float*)d_in[11];
  const float* Wc = (const float*)d_in[12];
  const float* bc = (const float*)d_in[13];

  float* out0 = (float*)d_out;                        // new_memory [8,2048,256]
  float* out1 = out0 + (size_t)8 * 2048 * 256;        // attention_probs [8,2048,2048]
  _Float16* ws = (_Float16*)d_ws;

  float* part = (float*)ws;                           // 256 KB at ws front (Q starts at byte 1 MB)
  const bool big = ws_size >= (size_t)26214400;       // Q+K+t+u fit in ws

  hipLaunchKernelGGL(k1_proj, dim3(256, 2), dim3(512), 0, stream,
                     input, prev, Wq, bq, Wk, bk, ws);

  if (big) {
    // t/u in ws tail -> k3b || k2ru race-free; k2c after kDE (needs full t/u)
    _Float16* t_sc = ws + OFF_T;
    _Float16* u_sc = ws + OFF_U;
    hipLaunchKernelGGL(k3a_sums, dim3(8, 16, 4), dim3(512), 0, stream, ws, part);
    hipLaunchKernelGGL(kDE, dim3(1024), dim3(512), 0, stream,
                       input, prev, Wr, br, Wu, bu, ws, part, t_sc, u_sc, out1);
    hipLaunchKernelGGL(k2c_kernel, dim3(512), dim3(512), 0, stream,
                       input, prev, Wc, bc, t_sc, u_sc, out0);
  } else {
    // serial path: t/u in out1 region, consumed (k2c) before k3b overwrites
    _Float16* t_sc = (_Float16*)out1;
    _Float16* u_sc = (_Float16*)out1 + 4194304;
    hipLaunchKernelGGL(k2ru_kernel, dim3(128, 4), dim3(512), 0, stream,
                       input, prev, Wr, br, Wu, bu, t_sc, u_sc);
    hipLaunchKernelGGL(k2c_kernel,  dim3(512), dim3(512), 0, stream,
                       input, prev, Wc, bc, t_sc, u_sc, out0);
    hipLaunchKernelGGL(k3a_sums,    dim3(8, 16, 4), dim3(512), 0, stream, ws, part);
    hipLaunchKernelGGL(k3b_kernel,  dim3(512), dim3(512), 0, stream, ws, part, out1);
  }
}

// Round 25
// 99.104 us; speedup vs baseline: 1.1881x; 1.1881x over previous
//
#include <hip/hip_runtime.h>

// DynamicMemoryCell: B=8, N=2048, IN=256, MEM=256, CTX=128
// out0 = new_memory [8,2048,256] f32 ; out1 = attention_probs [8,2048,2048] f32
// Wv/value/context dead in reference -> skipped.
//
// R24 = byte-exact revert to R22 (best measured: 99.3 us).
// Chain (big ws): k0 -> k1 -> k3a -> kDE=[k3b || k2ru] -> k2c.
// R23 (k0 deleted, in-register W conversion) regressed +18us: fp32 weight
// re-reads poisoned kDE's absorption. k0's ws fp16 cache keeps roles lean.
// Ledger: validated={q-tile>=128, K-via-LDS, absorb-largest-independent-into-
// longest}; refuted={k0 deletion, peer pairing x3, traffic substitution,
// cooperative fusion, finer blocks, role interleave/order, launch overhead}.

typedef _Float16 half8 __attribute__((ext_vector_type(8)));
typedef float floatx4 __attribute__((ext_vector_type(4)));

#define MFMA16(a, b, c) __builtin_amdgcn_mfma_f32_16x16x32_f16((a), (b), (c), 0, 0, 0)

// ws layout (units: _Float16)
#define OFF_WQH 0
#define OFF_WQL 32768
#define OFF_WKH 65536
#define OFF_WKL 98304
#define OFF_WUH 131072
#define OFF_WRH 262144
#define OFF_WCH 393216
#define OFF_Q   524288
#define OFF_K   2621440
#define OFF_T   4718592
#define OFF_U   8912896
// big-ws end = 13107200 halves = 26,214,400 bytes. part (f32 256 KB) aliases
// the dead WQ/WK hi-lo region after k1 consumes it.

__device__ __forceinline__ void gload16(const void* g, void* l) {
  __builtin_amdgcn_global_load_lds((const __attribute__((address_space(1))) unsigned int*)g,
                                   (__attribute__((address_space(3))) unsigned int*)l, 16, 0, 0);
}

// ---------------------------------------------------------------- K0: weights fp32 -> fp16 (hi/lo for Wq/Wk)
__global__ __launch_bounds__(256) void k0_convert(
    const float* __restrict__ Wq, const float* __restrict__ Wk,
    const float* __restrict__ Wu, const float* __restrict__ Wr,
    const float* __restrict__ Wc, _Float16* __restrict__ ws)
{
  int i = blockIdx.x * 256 + threadIdx.x;
  if (i < 32768) {
    float w = Wq[i];
    _Float16 h = (_Float16)w;
    ws[OFF_WQH + i] = h;
    ws[OFF_WQL + i] = (_Float16)(w - (float)h);
  } else if (i < 65536) {
    int j = i - 32768;
    float w = Wk[j];
    _Float16 h = (_Float16)w;
    ws[OFF_WKH + j] = h;
    ws[OFF_WKL + j] = (_Float16)(w - (float)h);
  } else {
    int j = i - 65536;
    if (j < 131072)      ws[OFF_WUH + j]            = (_Float16)Wu[j];
    else if (j < 262144) ws[OFF_WRH + (j - 131072)] = (_Float16)Wr[j - 131072];
    else                 ws[OFF_WCH + (j - 262144)] = (_Float16)Wc[j - 262144];
  }
}

// ---------------------------------------------------------------- K1: Q/K projection (2 products: W hi/lo, x fp16)
__global__ __launch_bounds__(512) void k1_proj(
    const float* __restrict__ input, const float* __restrict__ prev,
    const float* __restrict__ bq, const float* __restrict__ bk,
    _Float16* __restrict__ ws)
{
  __shared__ char smem[2 * 8192];   // 16 rows x 512B (x fp16)
  const int which = blockIdx.y;
  const float* x = which ? prev : input;
  const _Float16* WH = ws + (which ? OFF_WKH : OFF_WQH);
  const _Float16* WL = ws + (which ? OFF_WKL : OFF_WQL);
  const float* bias = which ? bk : bq;
  _Float16* out = ws + (which ? OFF_K : OFF_Q);

  const int tid = threadIdx.x, w = tid >> 6, l = tid & 63;
  const int lr = l & 15, lg = l >> 4;
  const int rows0 = blockIdx.x * 64;
  const int c = w * 16 + lr;

  half8 bh[8], blo[8];
#pragma unroll
  for (int ks = 0; ks < 8; ++ks) {
    bh[ks]  = *(const half8*)(WH + (size_t)c * 256 + ks * 32 + lg * 8);
    blo[ks] = *(const half8*)(WL + (size_t)c * 256 + ks * 32 + lg * 8);
  }
  const float bv = bias[c];

  const int srow = tid >> 5, scol = (tid & 31) * 8;
  const int ssz = (srow & 7) << 4;
  floatx4 st0, st1;

#define K1_LOAD(ch) { const float* src = x + ((size_t)rows0 + (ch) * 16 + srow) * 256 + scol; \
  st0 = *(const floatx4*)src; st1 = *(const floatx4*)(src + 4); }
#define K1_WRITE(ch) { char* bufw = smem + ((ch) & 1) * 8192; \
  half8 h; \
  _Pragma("unroll") for (int j = 0; j < 4; ++j) { \
    h[j] = (_Float16)st0[j]; h[4+j] = (_Float16)st1[j]; } \
  *(half8*)(bufw + srow * 512 + ((scol * 2) ^ ssz)) = h; }

  K1_LOAD(0); K1_WRITE(0);
  __syncthreads();
#pragma unroll 1
  for (int ch = 0; ch < 4; ++ch) {
    if (ch < 3) K1_LOAD(ch + 1);
    const char* buf = smem + (ch & 1) * 8192;
    floatx4 acc = {0.f, 0.f, 0.f, 0.f};
    const int base = lr * 512, sz = (lr & 7) << 4;
#pragma unroll
    for (int ks = 0; ks < 8; ++ks) {
      half8 ah = *(const half8*)(buf + base + ((ks * 64 + lg * 16) ^ sz));
      acc = MFMA16(ah, bh[ks], acc);
      acc = MFMA16(ah, blo[ks], acc);
    }
#pragma unroll
    for (int j = 0; j < 4; ++j)
      out[((size_t)rows0 + ch * 16 + lg * 4 + j) * 128 + c] = (_Float16)(acc[j] + bv);
    if (ch < 3) K1_WRITE(ch + 1);
    __syncthreads();
  }
}

// ================================================================ role bodies
// k2ru body: reset + update gates via wave groups. job = rowblk | colgrp<<7 (0..511).
__device__ __forceinline__ void k2ru_body(
    char* smem, int job, int tid,
    const float* __restrict__ input, const float* __restrict__ prev,
    const float* __restrict__ br, const float* __restrict__ bu,
    const _Float16* __restrict__ ws,
    _Float16* __restrict__ t_sc, _Float16* __restrict__ u_sc)
{
  const int w = tid >> 6, l = tid & 63;
  const int lr = l & 15, lg = l >> 4;
  const int rows0 = (job & 127) * 128;
  const int isU = w >> 2;
  const int c = (job >> 7) * 64 + (w & 3) * 16 + lr;

  const _Float16* W = ws + (isU ? OFF_WUH : OFF_WRH);
  half8 bw[16];
#pragma unroll
  for (int ks = 0; ks < 16; ++ks)
    bw[ks] = *(const half8*)(W + (size_t)c * 512 + ks * 32 + lg * 8);
  const float bv = (isU ? bu : br)[c];

  const int srow = tid >> 5, scol = (tid & 31) * 8;
  const int ssz = (srow & 7) << 4;
  floatx4 sI0, sI1, sP0, sP1;

#define K2RU_LOAD(ch) { \
  const float* si = input + ((size_t)rows0 + (ch) * 16 + srow) * 256 + scol; \
  const float* sp = prev  + ((size_t)rows0 + (ch) * 16 + srow) * 256 + scol; \
  sI0 = *(const floatx4*)si; sI1 = *(const floatx4*)(si + 4); \
  sP0 = *(const floatx4*)sp; sP1 = *(const floatx4*)(sp + 4); }
#define K2RU_WRITE(ch) { char* bufw = smem + ((ch) & 1) * 16384; \
  half8 hi, hp; \
  _Pragma("unroll") for (int j = 0; j < 4; ++j) { \
    hi[j] = (_Float16)sI0[j]; hi[4+j] = (_Float16)sI1[j]; \
    hp[j] = (_Float16)sP0[j]; hp[4+j] = (_Float16)sP1[j]; } \
  int o = srow * 1024 + ((scol * 2) ^ ssz); \
  *(half8*)(bufw + o) = hi; *(half8*)(bufw + o + 512) = hp; }

  K2RU_LOAD(0); K2RU_WRITE(0);
  __syncthreads();
#pragma unroll 1
  for (int ch = 0; ch < 8; ++ch) {
    if (ch < 7) K2RU_LOAD(ch + 1);
    const char* buf = smem + (ch & 1) * 16384;
    floatx4 acc = {0.f, 0.f, 0.f, 0.f};
    const int base = lr * 1024, sz = (lr & 7) << 4;
#pragma unroll
    for (int ks = 0; ks < 16; ++ks) {   // ks>=8 lands in [512,1024) = prev half
      half8 a = *(const half8*)(buf + base + ((ks * 64 + lg * 16) ^ sz));
      acc = MFMA16(a, bw[ks], acc);
    }
#pragma unroll
    for (int j = 0; j < 4; ++j) {
      const int crow = lg * 4 + j;
      const size_t grow = (size_t)rows0 + ch * 16 + crow;
      float g = 1.f / (1.f + __expf(-(acc[j] + bv)));
      if (!isU) {
        float m = (float)*(const _Float16*)(buf + crow * 1024 + 512 + ((c * 2) ^ ((crow & 7) << 4)));
        t_sc[grow * 256 + c] = (_Float16)(g * m);
      } else {
        u_sc[grow * 256 + c] = (_Float16)g;
      }
    }
    if (ch < 7) K2RU_WRITE(ch + 1);
    __syncthreads();
  }
}

// ---------------------------------------------------------------- shared macros for k2c / k3 roles
#define K2C_LOAD(ch) { \
  const float* si = input + ((size_t)rows0 + (ch) * 16 + srow) * 256 + scol; \
  sI0 = *(const floatx4*)si; sI1 = *(const floatx4*)(si + 4); \
  sT = *(const half8*)(t_sc + ((size_t)rows0 + (ch) * 16 + srow) * 256 + scol); }
#define K2C_WRITE(ch) { char* bufw = smemc + ((ch) & 1) * 16384; \
  half8 hi; \
  _Pragma("unroll") for (int j = 0; j < 4; ++j) { hi[j] = (_Float16)sI0[j]; hi[4+j] = (_Float16)sI1[j]; } \
  int o = srow * 1024 + ((scol * 2) ^ ssz); \
  *(half8*)(bufw + o) = hi; *(half8*)(bufw + o + 512) = sT; }

#define K3_STAGE(Kg, dst, ch) { \
  const char* g_ = (Kg) + (ch) * 32768; \
  _Pragma("unroll") for (int i_ = 0; i_ < 4; ++i_) { \
    int o_ = w * 1024 + i_ * 8192 + l * 16; \
    int row_ = o_ >> 8, col_ = o_ & 255; \
    gload16(g_ + row_ * 256 + (col_ ^ ((row_ & 7) << 4)), (dst) + w * 1024 + i_ * 8192); } }

// k2c body (candidate + combine -> out0)
__device__ __forceinline__ void k2c_body(
    char* smemc, int job, int tid,
    const float* __restrict__ input, const float* __restrict__ prev,
    const float* __restrict__ bc, const _Float16* __restrict__ ws,
    const _Float16* __restrict__ t_sc, const _Float16* __restrict__ u_sc,
    float* __restrict__ out0)
{
  const int w = tid >> 6, l = tid & 63;
  const int lr = l & 15, lg = l >> 4;
  const int rows0 = (job & 255) * 64;
  const int c = (job >> 8) * 128 + w * 16 + lr;

  half8 bw[16];
#pragma unroll
  for (int ks = 0; ks < 16; ++ks)
    bw[ks] = *(const half8*)(ws + OFF_WCH + (size_t)c * 512 + ks * 32 + lg * 8);
  const float bv = bc[c];

  const int srow = tid >> 5, scol = (tid & 31) * 8;
  const int ssz = (srow & 7) << 4;
  floatx4 sI0, sI1;
  half8 sT;

  K2C_LOAD(0); K2C_WRITE(0);
  __syncthreads();
#pragma unroll 1
  for (int ch = 0; ch < 4; ++ch) {
    if (ch < 3) K2C_LOAD(ch + 1);
    const char* buf = smemc + (ch & 1) * 16384;
    floatx4 acc = {0.f, 0.f, 0.f, 0.f};
    const int base = lr * 1024, sz = (lr & 7) << 4;
#pragma unroll
    for (int ks = 0; ks < 16; ++ks) {   // ks>=8 = t half
      half8 a = *(const half8*)(buf + base + ((ks * 64 + lg * 16) ^ sz));
      acc = MFMA16(a, bw[ks], acc);
    }
#pragma unroll
    for (int j = 0; j < 4; ++j) {
      const size_t grow = (size_t)rows0 + ch * 16 + lg * 4 + j;
      float e2 = __expf(2.f * (acc[j] + bv));
      float cg = (e2 - 1.f) / (e2 + 1.f);
      float u = (float)u_sc[grow * 256 + c];
      float m = prev[grow * 256 + c];
      out0[grow * 256 + c] = (1.f - u) * m + u * cg;
    }
    if (ch < 3) K2C_WRITE(ch + 1);
    __syncthreads();
  }
}

// k3b body (recompute + normalize + store out1)
__device__ __forceinline__ void k3b_body(
    char* smem, int job, int tid,
    const _Float16* __restrict__ ws, const float* __restrict__ part,
    float* __restrict__ out1)
{
  const int w = tid >> 6, l = tid & 63;
  const int lr = l & 15, lg = l >> 4;
  const int b = job & 7, q0 = ((job >> 3) & 15) * 128, kh = job >> 7;

  const int q = q0 + w * 16 + lr;
  const _Float16* Q = ws + OFF_Q + ((size_t)b * 2048 + q0 + w * 16) * 128;
  const char* Kg = (const char*)(ws + OFF_K + ((size_t)b * 2048 + kh * 512) * 128);

  half8 qf[4];
#pragma unroll
  for (int ks = 0; ks < 4; ++ks)
    qf[ks] = *(const half8*)(Q + (size_t)lr * 128 + ks * 32 + lg * 8);
  const float inv = 1.f / (part[(size_t)(b * 4 + 0) * 2048 + q] +
                           part[(size_t)(b * 4 + 1) * 2048 + q] +
                           part[(size_t)(b * 4 + 2) * 2048 + q] +
                           part[(size_t)(b * 4 + 3) * 2048 + q]);

  char* kbuf0 = smem; char* kbuf1 = smem + 32768;
  K3_STAGE(Kg, kbuf0, 0);
  __syncthreads();

  float* orow = out1 + ((size_t)b * 2048 + q) * 2048 + kh * 512;
#pragma unroll 1
  for (int ch = 0; ch < 4; ++ch) {
    if (ch < 3) K3_STAGE(Kg, ((ch + 1) & 1) ? kbuf1 : kbuf0, ch + 1);
    const char* buf = (ch & 1) ? kbuf1 : kbuf0;
#pragma unroll
    for (int kt = 0; kt < 8; ++kt) {
      const int kk = kt * 16 + lr;
      const int kbase = kk * 256, ksz = (kk & 7) << 4;
      half8 kf[4];
#pragma unroll
      for (int ks = 0; ks < 4; ++ks)
        kf[ks] = *(const half8*)(buf + kbase + ((ks * 64 + lg * 16) ^ ksz));
      floatx4 acc = {0.f, 0.f, 0.f, 0.f};
#pragma unroll
      for (int ks = 0; ks < 4; ++ks) acc = MFMA16(kf[ks], qf[ks], acc);
      floatx4 v;
#pragma unroll
      for (int j = 0; j < 4; ++j) v[j] = __expf(acc[j] - 14.f) * inv;
      *(floatx4*)(orow + ch * 128 + kt * 16 + lg * 4) = v;
    }
    __syncthreads();
  }
}

// ---------------------------------------------------------------- K3a: softmax row-sums (pass 1)
// grid (8, 16, 4) x 512. Block = 128 q-rows x 512 keys. 8 waves split q (16 rows each).
__global__ __launch_bounds__(512) void k3a_sums(
    const _Float16* __restrict__ ws, float* __restrict__ part)
{
  __shared__ char kbuf[2][32768];
  const int b = blockIdx.x, q0 = blockIdx.y * 128, kh = blockIdx.z;
  const int tid = threadIdx.x, w = tid >> 6, l = tid & 63;
  const int lr = l & 15, lg = l >> 4;

  const _Float16* Q = ws + OFF_Q + ((size_t)b * 2048 + q0 + w * 16) * 128;
  const char* Kg = (const char*)(ws + OFF_K + ((size_t)b * 2048 + kh * 512) * 128);

  half8 qf[4];
#pragma unroll
  for (int ks = 0; ks < 4; ++ks)
    qf[ks] = *(const half8*)(Q + (size_t)lr * 128 + ks * 32 + lg * 8);

  K3_STAGE(Kg, kbuf[0], 0);
  __syncthreads();

  float se = 0.f;
#pragma unroll 1
  for (int ch = 0; ch < 4; ++ch) {
    if (ch < 3) K3_STAGE(Kg, kbuf[(ch + 1) & 1], ch + 1);
    const char* buf = kbuf[ch & 1];
#pragma unroll
    for (int kt = 0; kt < 8; ++kt) {
      const int kk = kt * 16 + lr;
      const int kbase = kk * 256, ksz = (kk & 7) << 4;
      half8 kf[4];
#pragma unroll
      for (int ks = 0; ks < 4; ++ks)
        kf[ks] = *(const half8*)(buf + kbase + ((ks * 64 + lg * 16) ^ ksz));
      floatx4 acc = {0.f, 0.f, 0.f, 0.f};
#pragma unroll
      for (int ks = 0; ks < 4; ++ks) acc = MFMA16(kf[ks], qf[ks], acc);
#pragma unroll
      for (int j = 0; j < 4; ++j) se += __expf(acc[j] - 14.f);
    }
    __syncthreads();
  }
  se += __shfl_xor(se, 16);
  se += __shfl_xor(se, 32);
  if (lg == 0)
    part[((size_t)b * 4 + kh) * 2048 + q0 + w * 16 + lr] = se;
}

// ---------------------------------------------------------------- fat kDE = [k3b (first 512) || k2ru (next 512)]
// Independent: k3b reads Q/K/part, writes out1; k2ru reads input/prev/ws-weights,
// writes t/u in ws tail. Disjoint. Long-job-first ordering (k3b blocks dispatch first).
__global__ __launch_bounds__(512, 4) void kDE(
    const float* __restrict__ input, const float* __restrict__ prev,
    const float* __restrict__ br, const float* __restrict__ bu,
    const _Float16* __restrict__ ws, const float* __restrict__ part,
    _Float16* __restrict__ t_sc, _Float16* __restrict__ u_sc,
    float* __restrict__ out1)
{
  __shared__ char smem[65536];
  if (blockIdx.x < 512)
    k3b_body(smem, blockIdx.x, threadIdx.x, ws, part, out1);
  else
    k2ru_body(smem, blockIdx.x - 512, threadIdx.x, input, prev, br, bu, ws, t_sc, u_sc);
}

// ---------------------------------------------------------------- standalone kernels
__global__ __launch_bounds__(512) void k2ru_kernel(
    const float* __restrict__ input, const float* __restrict__ prev,
    const float* __restrict__ br, const float* __restrict__ bu,
    const _Float16* __restrict__ ws,
    _Float16* __restrict__ t_sc, _Float16* __restrict__ u_sc)
{
  __shared__ char smem[2 * 16384];
  k2ru_body(smem, (blockIdx.y << 7) | blockIdx.x, threadIdx.x, input, prev, br, bu, ws, t_sc, u_sc);
}

__global__ __launch_bounds__(512) void k2c_kernel(
    const float* __restrict__ input, const float* __restrict__ prev,
    const float* __restrict__ bc, const _Float16* __restrict__ ws,
    const _Float16* __restrict__ t_sc, const _Float16* __restrict__ u_sc,
    float* __restrict__ out0)
{
  __shared__ char smemc[2 * 16384];
  k2c_body(smemc, blockIdx.x, threadIdx.x, input, prev, bc, ws, t_sc, u_sc, out0);
}

__global__ __launch_bounds__(512) void k3b_kernel(
    const _Float16* __restrict__ ws, const float* __restrict__ part,
    float* __restrict__ out1)
{
  __shared__ char smem[65536];
  k3b_body(smem, blockIdx.x, threadIdx.x, ws, part, out1);
}

// ----------------------------------------------------------------
extern "C" void kernel_launch(void* const* d_in, const int* in_sizes, int n_in,
                              void* d_out, int out_size, void* d_ws, size_t ws_size,
                              hipStream_t stream)
{
  const float* input = (const float*)d_in[0];
  const float* prev  = (const float*)d_in[1];
  const float* Wq = (const float*)d_in[2];
  const float* bq = (const float*)d_in[3];
  const float* Wk = (const float*)d_in[4];
  const float* bk = (const float*)d_in[5];
  const float* Wu = (const float*)d_in[8];
  const float* bu = (const float*)d_in[9];
  const float* Wr = (const float*)d_in[10];
  const float* br = (const float*)d_in[11];
  const float* Wc = (const float*)d_in[12];
  const float* bc = (const float*)d_in[13];

  float* out0 = (float*)d_out;                        // new_memory [8,2048,256]
  float* out1 = out0 + (size_t)8 * 2048 * 256;        // attention_probs [8,2048,2048]
  _Float16* ws = (_Float16*)d_ws;

  float* part = (float*)ws;                           // 256 KB, aliases dead WQ/WK hi-lo after k1
  const bool big = ws_size >= (size_t)26214400;       // Q+K+t+u fit in ws

  hipLaunchKernelGGL(k0_convert, dim3(1792), dim3(256), 0, stream, Wq, Wk, Wu, Wr, Wc, ws);
  hipLaunchKernelGGL(k1_proj,    dim3(256, 2), dim3(512), 0, stream, input, prev, bq, bk, ws);

  if (big) {
    // t/u in ws tail -> k3b || k2ru race-free; k2c after kDE (needs full t/u)
    _Float16* t_sc = ws + OFF_T;
    _Float16* u_sc = ws + OFF_U;
    hipLaunchKernelGGL(k3a_sums, dim3(8, 16, 4), dim3(512), 0, stream, ws, part);
    hipLaunchKernelGGL(kDE, dim3(1024), dim3(512), 0, stream,
                       input, prev, br, bu, ws, part, t_sc, u_sc, out1);
    hipLaunchKernelGGL(k2c_kernel, dim3(512), dim3(512), 0, stream,
                       input, prev, bc, ws, t_sc, u_sc, out0);
  } else {
    // serial path: t/u in out1 region, consumed (k2c) before k3b overwrites
    _Float16* t_sc = (_Float16*)out1;
    _Float16* u_sc = (_Float16*)out1 + 4194304;
    hipLaunchKernelGGL(k2ru_kernel, dim3(128, 4), dim3(512), 0, stream,
                       input, prev, br, bu, ws, t_sc, u_sc);
    hipLaunchKernelGGL(k2c_kernel,  dim3(512), dim3(512), 0, stream,
                       input, prev, bc, ws, t_sc, u_sc, out0);
    hipLaunchKernelGGL(k3a_sums,    dim3(8, 16, 4), dim3(512), 0, stream, ws, part);
    hipLaunchKernelGGL(k3b_kernel,  dim3(512), dim3(512), 0, stream, ws, part, out1);
  }
}